// Round 1
// baseline (33676.315 us; speedup 1.0000x reference)
//
#include <hip/hip_runtime.h>
#include <math.h>

#define DIM   768
#define NHEAD 16
#define DHEAD 48
#define NLAY  3
#define NTOK  256
#define BATCH 4
#define NPAST_ 16
#define NFUT  20
#define CCTX  273              // NTOK + 1 + NPAST
#define SMAXT 293              // CCTX + NFUT
#define MROWS 1172             // BATCH * SMAXT
#define NEGV  (-1.0e9f)

__device__ inline float gelu_f(float x) {
    return 0.5f * x * (1.0f + erff(x * 0.70710678118654752f));
}

// ---------------------------------------------------------------- init X_base
__global__ void init_base(const float* __restrict__ img, const float* __restrict__ past,
                          const int* __restrict__ intent, const float* __restrict__ pos,
                          const float* __restrict__ futq, const float* __restrict__ iemb,
                          const float* __restrict__ temb, const float* __restrict__ Wp,
                          const float* __restrict__ bp, const float* __restrict__ Wpp,
                          const float* __restrict__ bpp, float* __restrict__ X)
{
    int r = blockIdx.x;                 // 0..MROWS-1
    int b = r / SMAXT, s = r % SMAXT;
    for (int j = threadIdx.x; j < DIM; j += blockDim.x) {
        float v;
        if (s < NTOK) {
            v = img[(long)(b * NTOK + s) * DIM + j] + pos[(long)s * DIM + j];
        } else if (s == NTOK) {
            int idx = intent[b] - 1; idx = idx < 0 ? 0 : (idx > 2 ? 2 : idx);
            v = iemb[(long)idx * DIM + j];
        } else if (s < CCTX) {
            int i = s - (NTOK + 1);
            v = bp[j] + bpp[j] + temb[(long)i * DIM + j];
            const float* pr = past + (long)(b * NPAST_ + i) * 6;
            #pragma unroll
            for (int c = 0; c < 6; ++c) v += pr[c] * Wp[(long)c * DIM + j];
            v += pr[0] * Wpp[j] + pr[1] * Wpp[DIM + j];
        } else {
            int f = s - CCTX;
            v = futq[(long)f * DIM + j] + temb[(long)(NPAST_ + f) * DIM + j];
        }
        X[(long)r * DIM + j] = v;
    }
}

// ---------------------------------------------------------------- layernorm
__launch_bounds__(256)
__global__ void ln_kernel(const float* __restrict__ x, const float* __restrict__ g,
                          const float* __restrict__ be, float* __restrict__ y)
{
    int row = blockIdx.x * 4 + (threadIdx.x >> 6);
    int lane = threadIdx.x & 63;
    if (row >= MROWS) return;
    const float* xr = x + (long)row * DIM;
    float v[12];
    float s = 0.f;
    #pragma unroll
    for (int i = 0; i < 12; ++i) { v[i] = xr[lane + 64 * i]; s += v[i]; }
    for (int off = 32; off; off >>= 1) s += __shfl_down(s, off, 64);
    s = __shfl(s, 0, 64);
    float mean = s * (1.f / 768.f);
    float vs = 0.f;
    #pragma unroll
    for (int i = 0; i < 12; ++i) { float d = v[i] - mean; vs += d * d; }
    for (int off = 32; off; off >>= 1) vs += __shfl_down(vs, off, 64);
    vs = __shfl(vs, 0, 64);
    float inv = rsqrtf(vs * (1.f / 768.f) + 1e-5f);
    float* yr = y + (long)row * DIM;
    #pragma unroll
    for (int i = 0; i < 12; ++i) {
        int j = lane + 64 * i;
        yr[j] = (v[i] - mean) * inv * g[j] + be[j];
    }
}

// ---------------------------------------------------------------- fp32 GEMM
// C[M,N] = A[M,K] @ W[K,N] + bias (+res) (relu)
template<bool RELU, bool RES>
__launch_bounds__(256)
__global__ void gemm_kernel(const float* __restrict__ A, const float* __restrict__ W,
                            const float* __restrict__ bias, const float* __restrict__ res,
                            float* __restrict__ Cout, int M, int N, int K)
{
    __shared__ float As[16][68];   // [k][m]
    __shared__ float Ws[16][64];   // [k][n]
    int t = threadIdx.x;
    int tx = t & 15, ty = t >> 4;
    int n0 = blockIdx.x * 64, m0 = blockIdx.y * 64;
    int arow = t >> 2;             // 0..63
    int akk  = (t & 3) * 4;        // 0,4,8,12
    int aRowG = m0 + arow; if (aRowG >= M) aRowG = M - 1;
    const float* Aptr = A + (long)aRowG * K + akk;
    int wrow = t >> 4;             // 0..15
    int wcol = (t & 15) * 4;       // 0..60
    const float* Wptr = W + (long)wrow * N + n0 + wcol;
    float acc[4][4] = {};
    for (int k0 = 0; k0 < K; k0 += 16) {
        float4 a4 = *(const float4*)(Aptr + k0);
        float4 w4 = *(const float4*)(Wptr + (long)k0 * N);
        __syncthreads();
        As[akk + 0][arow] = a4.x; As[akk + 1][arow] = a4.y;
        As[akk + 2][arow] = a4.z; As[akk + 3][arow] = a4.w;
        *(float4*)&Ws[wrow][wcol] = w4;
        __syncthreads();
        #pragma unroll
        for (int k = 0; k < 16; ++k) {
            float4 av = *(const float4*)&As[k][ty * 4];
            float4 wv = *(const float4*)&Ws[k][tx * 4];
            acc[0][0] += av.x * wv.x; acc[0][1] += av.x * wv.y; acc[0][2] += av.x * wv.z; acc[0][3] += av.x * wv.w;
            acc[1][0] += av.y * wv.x; acc[1][1] += av.y * wv.y; acc[1][2] += av.y * wv.z; acc[1][3] += av.y * wv.w;
            acc[2][0] += av.z * wv.x; acc[2][1] += av.z * wv.y; acc[2][2] += av.z * wv.z; acc[2][3] += av.z * wv.w;
            acc[3][0] += av.w * wv.x; acc[3][1] += av.w * wv.y; acc[3][2] += av.w * wv.z; acc[3][3] += av.w * wv.w;
        }
    }
    float4 b4 = *(const float4*)&bias[n0 + tx * 4];
    #pragma unroll
    for (int i = 0; i < 4; ++i) {
        int r = m0 + ty * 4 + i;
        if (r < M) {
            float4 o;
            o.x = acc[i][0] + b4.x; o.y = acc[i][1] + b4.y;
            o.z = acc[i][2] + b4.z; o.w = acc[i][3] + b4.w;
            if (RES) {
                float4 rv = *(const float4*)&res[(long)r * N + n0 + tx * 4];
                o.x += rv.x; o.y += rv.y; o.z += rv.z; o.w += rv.w;
            }
            if (RELU) {
                o.x = fmaxf(o.x, 0.f); o.y = fmaxf(o.y, 0.f);
                o.z = fmaxf(o.z, 0.f); o.w = fmaxf(o.w, 0.f);
            }
            *(float4*)&Cout[(long)r * N + n0 + tx * 4] = o;
        }
    }
}

// ---------------------------------------------------------------- attention
// qkv: [MROWS, 2304] (q|k|v per row). o: [MROWS, 768]. One block = (b,h,16 q rows).
__launch_bounds__(256)
__global__ void attn_kernel(const float* __restrict__ qkv, float* __restrict__ o, int S)
{
    int b = blockIdx.y >> 4, h = blockIdx.y & 15;
    int q0 = blockIdx.x * 16;
    if (q0 >= S) return;
    __shared__ float qs[16][48];
    __shared__ float kbuf[3328];        // Ks[64][52]  OR  VsT[48][68]
    __shared__ float sc[16][304];
    int t = threadIdx.x;
    const float scale = 0.14433756729740643f;   // 1/sqrt(48)
    for (int lin = t; lin < 16 * 48; lin += 256) {
        int i = lin / 48, d = lin % 48;
        int qi2 = q0 + i; if (qi2 > SMAXT - 1) qi2 = SMAXT - 1;
        qs[i][d] = qkv[((long)(b * SMAXT + qi2)) * 2304 + h * 48 + d] * scale;
    }
    __syncthreads();
    int i = t >> 4, j = t & 15;
    int qi = q0 + i;
    float4 q4[12];
    #pragma unroll
    for (int k4 = 0; k4 < 12; ++k4) q4[k4] = *(const float4*)&qs[i][k4 * 4];

    // ---- scores
    for (int s0 = 0; s0 < S; s0 += 64) {
        int ns = S - s0; if (ns > 64) ns = 64;
        __syncthreads();
        for (int lin = t; lin < 64 * 48; lin += 256) {
            int ss = lin / 48, d = lin % 48;
            float v = 0.f;
            if (ss < ns) v = qkv[((long)(b * SMAXT + s0 + ss)) * 2304 + 768 + h * 48 + d];
            kbuf[ss * 52 + d] = v;
        }
        __syncthreads();
        #pragma unroll
        for (int u = 0; u < 4; ++u) {
            int ss = j + 16 * u;
            float acc = 0.f;
            #pragma unroll
            for (int k4 = 0; k4 < 12; ++k4) {
                float4 kk = *(const float4*)&kbuf[ss * 52 + k4 * 4];
                acc += q4[k4].x * kk.x + q4[k4].y * kk.y + q4[k4].z * kk.z + q4[k4].w * kk.w;
            }
            int s = s0 + ss;
            if (ss < ns) {
                bool masked = (qi >= CCTX) && (s > qi);
                sc[i][s] = masked ? acc + NEGV : acc;
            }
        }
    }
    __syncthreads();

    // ---- softmax (row i handled by its 16 lanes, same wave)
    float mx = -1e30f;
    for (int s = j; s < S; s += 16) mx = fmaxf(mx, sc[i][s]);
    #pragma unroll
    for (int m = 8; m; m >>= 1) mx = fmaxf(mx, __shfl_xor(mx, m, 16));
    int Sp = (S + 3) & ~3;
    float sum = 0.f;
    for (int s = j; s < Sp; s += 16) {
        float e = (s < S) ? __expf(sc[i][s] - mx) : 0.f;
        sc[i][s] = e; sum += e;
    }
    #pragma unroll
    for (int m = 8; m; m >>= 1) sum += __shfl_xor(sum, m, 16);
    float inv = 1.f / sum;

    // ---- o = softmax @ V
    float oc0 = 0.f, oc1 = 0.f, oc2 = 0.f;
    int d0 = j * 3;
    for (int s0 = 0; s0 < S; s0 += 64) {
        int ns4 = Sp - s0; if (ns4 > 64) ns4 = 64;
        __syncthreads();
        for (int lin = t; lin < 64 * 48; lin += 256) {
            int ss = lin / 48, d = lin % 48;
            float v = 0.f;
            int s = s0 + ss;
            if (s < S) v = qkv[((long)(b * SMAXT + s)) * 2304 + 1536 + h * 48 + d];
            kbuf[d * 68 + ss] = v;     // transposed
        }
        __syncthreads();
        for (int sb = 0; sb < ns4; sb += 4) {
            float4 a4 = *(const float4*)&sc[i][s0 + sb];
            float4 v0 = *(const float4*)&kbuf[d0 * 68 + sb];
            float4 v1 = *(const float4*)&kbuf[(d0 + 1) * 68 + sb];
            float4 v2 = *(const float4*)&kbuf[(d0 + 2) * 68 + sb];
            oc0 += a4.x * v0.x + a4.y * v0.y + a4.z * v0.z + a4.w * v0.w;
            oc1 += a4.x * v1.x + a4.y * v1.y + a4.z * v1.z + a4.w * v1.w;
            oc2 += a4.x * v2.x + a4.y * v2.y + a4.z * v2.z + a4.w * v2.w;
        }
    }
    if (qi < S) {
        float* orow = o + ((long)(b * SMAXT + qi)) * 768 + h * 48 + d0;
        orow[0] = oc0 * inv; orow[1] = oc1 * inv; orow[2] = oc2 * inv;
    }
}

// ---------------------------------------------------------------- decoder gelu GEMM (4x768 @ 768x768)
__launch_bounds__(256)
__global__ void dec_gelu(const float* __restrict__ src, long srowstride,
                         const float* __restrict__ W, const float* __restrict__ bias,
                         float* __restrict__ dst)
{
    int b = blockIdx.y;           // 0..3
    int jb = blockIdx.x;          // 0..11
    __shared__ float s0buf[768];
    __shared__ float red[4][64];
    int tid = threadIdx.x;
    const float* sr = src + (long)b * srowstride;
    for (int i = tid; i < 768; i += 256) s0buf[i] = sr[i];
    __syncthreads();
    int jj = tid & 63, ig = tid >> 6;
    int jcol = jb * 64 + jj;
    float acc = 0.f;
    const float* wp = W + (long)(ig * 192) * 768 + jcol;
    #pragma unroll 4
    for (int i = 0; i < 192; ++i) acc += s0buf[ig * 192 + i] * wp[(long)i * 768];
    red[ig][jj] = acc;
    __syncthreads();
    if (ig == 0) {
        float a = red[0][jj] + red[1][jj] + red[2][jj] + red[3][jj] + bias[jcol];
        dst[(long)b * 768 + jcol] = gelu_f(a);
    }
}

// ---------------------------------------------------------------- decoder final: p, preds, future-token update
__launch_bounds__(256)
__global__ void dec_final(const float* __restrict__ d2, const float* __restrict__ Wd3,
                          const float* __restrict__ bd3, const float* __restrict__ Wpp,
                          const float* __restrict__ bpp, const float* __restrict__ gpp,
                          const float* __restrict__ bepp, float* __restrict__ out,
                          float* __restrict__ X, int t)
{
    int b = blockIdx.x;
    int tid = threadIdx.x;
    __shared__ float red[2][4];
    __shared__ float pp[2];
    const float* dr = d2 + (long)b * 768;
    float a0 = 0.f, a1 = 0.f;
    for (int i = tid; i < 768; i += 256) {
        float v = dr[i];
        a0 += v * Wd3[2 * i]; a1 += v * Wd3[2 * i + 1];
    }
    for (int off = 32; off; off >>= 1) { a0 += __shfl_down(a0, off, 64); a1 += __shfl_down(a1, off, 64); }
    int wid = tid >> 6, lane = tid & 63;
    if (!lane) { red[0][wid] = a0; red[1][wid] = a1; }
    __syncthreads();
    if (!tid) {
        float p0 = red[0][0] + red[0][1] + red[0][2] + red[0][3] + bd3[0];
        float p1 = red[1][0] + red[1][1] + red[1][2] + red[1][3] + bd3[1];
        out[(long)(b * NFUT + t) * 2 + 0] = p0;
        out[(long)(b * NFUT + t) * 2 + 1] = p1;
        pp[0] = p0; pp[1] = p1;
    }
    __syncthreads();
    if (t == NFUT - 1) return;
    float p0 = pp[0], p1 = pp[1];
    float pv[3]; float s = 0.f;
    #pragma unroll
    for (int u = 0; u < 3; ++u) {
        int jcol = tid + 256 * u;
        pv[u] = p0 * Wpp[jcol] + p1 * Wpp[768 + jcol] + bpp[jcol];
        s += pv[u];
    }
    for (int off = 32; off; off >>= 1) s += __shfl_down(s, off, 64);
    __syncthreads();
    if (!lane) red[0][wid] = s;
    __syncthreads();
    float mean = (red[0][0] + red[0][1] + red[0][2] + red[0][3]) * (1.f / 768.f);
    float vs = 0.f;
    #pragma unroll
    for (int u = 0; u < 3; ++u) { float d = pv[u] - mean; vs += d * d; }
    for (int off = 32; off; off >>= 1) vs += __shfl_down(vs, off, 64);
    __syncthreads();
    if (!lane) red[1][wid] = vs;
    __syncthreads();
    float var = (red[1][0] + red[1][1] + red[1][2] + red[1][3]) * (1.f / 768.f);
    float inv = rsqrtf(var + 1e-5f);
    float* Xr = X + ((long)(b * SMAXT + CCTX + t + 1)) * 768;
    #pragma unroll
    for (int u = 0; u < 3; ++u) {
        int jcol = tid + 256 * u;
        float y = (pv[u] - mean) * inv * gpp[jcol] + bepp[jcol];
        if (y > 0.f) Xr[jcol] += y;
    }
}

// ---------------------------------------------------------------- launch
extern "C" void kernel_launch(void* const* d_in, const int* in_sizes, int n_in,
                              void* d_out, int out_size, void* d_ws, size_t ws_size,
                              hipStream_t stream)
{
    const float* img    = (const float*)d_in[0];
    const float* past   = (const float*)d_in[1];
    const int*   intent = (const int*)d_in[2];
    const float* pos    = (const float*)d_in[3];
    const float* futq   = (const float*)d_in[4];
    const float* iemb   = (const float*)d_in[5];
    const float* temb   = (const float*)d_in[6];
    const float* W_past = (const float*)d_in[7];
    const float* b_past = (const float*)d_in[8];
    const float* W_ppos = (const float*)d_in[9];
    const float* b_ppos = (const float*)d_in[10];
    const float* W_pp   = (const float*)d_in[11];
    const float* b_pp   = (const float*)d_in[12];
    const float* g_pp   = (const float*)d_in[13];
    const float* be_pp  = (const float*)d_in[14];
    const float* Wqkv   = (const float*)d_in[15];
    const float* bqkv   = (const float*)d_in[16];
    const float* Wo     = (const float*)d_in[17];
    const float* bo     = (const float*)d_in[18];
    const float* g1     = (const float*)d_in[19];
    const float* beta1  = (const float*)d_in[20];
    const float* g2     = (const float*)d_in[21];
    const float* beta2  = (const float*)d_in[22];
    const float* W1     = (const float*)d_in[23];
    const float* bf1    = (const float*)d_in[24];
    const float* W2     = (const float*)d_in[25];
    const float* bf2    = (const float*)d_in[26];
    const float* Wd1    = (const float*)d_in[27];
    const float* bd1    = (const float*)d_in[28];
    const float* Wd2    = (const float*)d_in[29];
    const float* bd2    = (const float*)d_in[30];
    const float* Wd3    = (const float*)d_in[31];
    const float* bd3    = (const float*)d_in[32];
    float* out = (float*)d_out;

    float* ws    = (float*)d_ws;
    float* Xb    = ws;                       // 1172*768
    float* xbuf  = ws + 900096;              // 1172*768
    float* hbuf  = ws + 1800192;             // 1172*768
    float* aobuf = ws + 2700288;             // 1172*768
    float* big   = ws + 3600384;             // 1172*3072 (qkv / ffn1)
    float* d1ws  = ws + 7200768;             // 4*768
    float* d2ws  = ws + 7203840;             // 4*768

    init_base<<<dim3(MROWS), dim3(256), 0, stream>>>(img, past, intent, pos, futq, iemb,
                                                     temb, W_past, b_past, W_ppos, b_ppos, Xb);

    for (int t = 0; t < NFUT; ++t) {
        int S = CCTX + t + 1;
        const float* src = Xb;
        for (int l = 0; l < NLAY; ++l) {
            ln_kernel<<<dim3(293), dim3(256), 0, stream>>>(src, g1 + l * 768, beta1 + l * 768, hbuf);
            gemm_kernel<false, false><<<dim3(36, 19), dim3(256), 0, stream>>>(
                hbuf, Wqkv + (long)l * 768 * 2304, bqkv + l * 2304, nullptr, big, MROWS, 2304, 768);
            attn_kernel<<<dim3((S + 15) / 16, 64), dim3(256), 0, stream>>>(big, aobuf, S);
            gemm_kernel<false, true><<<dim3(12, 19), dim3(256), 0, stream>>>(
                aobuf, Wo + (long)l * 768 * 768, bo + l * 768, src, xbuf, MROWS, 768, 768);
            ln_kernel<<<dim3(293), dim3(256), 0, stream>>>(xbuf, g2 + l * 768, beta2 + l * 768, hbuf);
            gemm_kernel<true, false><<<dim3(48, 19), dim3(256), 0, stream>>>(
                hbuf, W1 + (long)l * 768 * 3072, bf1 + l * 3072, nullptr, big, MROWS, 3072, 768);
            gemm_kernel<false, true><<<dim3(12, 19), dim3(256), 0, stream>>>(
                big, W2 + (long)l * 3072 * 768, bf2 + l * 768, xbuf, xbuf, MROWS, 768, 3072);
            src = xbuf;
        }
        dec_gelu<<<dim3(12, 4), dim3(256), 0, stream>>>(xbuf + (long)(S - 1) * 768, (long)SMAXT * 768, Wd1, bd1, d1ws);
        dec_gelu<<<dim3(12, 4), dim3(256), 0, stream>>>(d1ws, 768L, Wd2, bd2, d2ws);
        dec_final<<<dim3(4), dim3(256), 0, stream>>>(d2ws, Wd3, bd3, W_pp, b_pp, g_pp, be_pp, out, Xb, t);
    }
}

// Round 2
// 13619.775 us; speedup vs baseline: 2.4726x; 2.4726x over previous
//
#include <hip/hip_runtime.h>
#include <math.h>

#define DIM   768
#define NHEAD 16
#define DHEAD 48
#define NLAY  3
#define NTOK  256
#define BATCH 4
#define NPAST_ 16
#define NFUT  20
#define CCTX  273              // NTOK + 1 + NPAST
#define SMAXT 293              // CCTX + NFUT
#define MROWS 1172             // BATCH * SMAXT
#define NEGV  (-1.0e9f)
#define QKVPLANE 900096        // BATCH*NHEAD*SMAXT*48

typedef unsigned short u16;
typedef unsigned int   u32;
typedef __attribute__((ext_vector_type(8))) short short8;
typedef __attribute__((ext_vector_type(4))) float floatx4;

__device__ inline u16 f2bf(float x) {
    union { float f; u32 u; } v; v.f = x;
    u32 r = v.u + 0x7fffu + ((v.u >> 16) & 1u);
    return (u16)(r >> 16);
}

__device__ inline float gelu_f(float x) {
    return 0.5f * x * (1.0f + erff(x * 0.70710678118654752f));
}

// ---------------------------------------------------------------- init X_base
__global__ void init_base(const float* __restrict__ img, const float* __restrict__ past,
                          const int* __restrict__ intent, const float* __restrict__ pos,
                          const float* __restrict__ futq, const float* __restrict__ iemb,
                          const float* __restrict__ temb, const float* __restrict__ Wp,
                          const float* __restrict__ bp, const float* __restrict__ Wpp,
                          const float* __restrict__ bpp, float* __restrict__ X)
{
    int r = blockIdx.x;
    int b = r / SMAXT, s = r % SMAXT;
    for (int j = threadIdx.x; j < DIM; j += blockDim.x) {
        float v;
        if (s < NTOK) {
            v = img[(long)(b * NTOK + s) * DIM + j] + pos[(long)s * DIM + j];
        } else if (s == NTOK) {
            int idx = intent[b] - 1; idx = idx < 0 ? 0 : (idx > 2 ? 2 : idx);
            v = iemb[(long)idx * DIM + j];
        } else if (s < CCTX) {
            int i = s - (NTOK + 1);
            v = bp[j] + bpp[j] + temb[(long)i * DIM + j];
            const float* pr = past + (long)(b * NPAST_ + i) * 6;
            #pragma unroll
            for (int c = 0; c < 6; ++c) v += pr[c] * Wp[(long)c * DIM + j];
            v += pr[0] * Wpp[j] + pr[1] * Wpp[DIM + j];
        } else {
            int f = s - CCTX;
            v = futq[(long)f * DIM + j] + temb[(long)(NPAST_ + f) * DIM + j];
        }
        X[(long)r * DIM + j] = v;
    }
}

// ---------------------------------------------------------------- weight convert + transpose: W[K,N] fp32 -> Wt[N,K] bf16
__global__ void convert_transpose(const float* __restrict__ W, u16* __restrict__ Wt, int K, int N)
{
    __shared__ float tile[32][33];
    long lstride = (long)K * N;
    W  += blockIdx.z * lstride;
    Wt += blockIdx.z * lstride;
    int n0 = blockIdx.x * 32, k0 = blockIdx.y * 32;
    int tx = threadIdx.x & 31, ty = threadIdx.x >> 5;
    for (int i = ty; i < 32; i += 8)
        tile[i][tx] = W[(long)(k0 + i) * N + n0 + tx];
    __syncthreads();
    for (int i = ty; i < 32; i += 8)
        Wt[(long)(n0 + i) * K + k0 + tx] = f2bf(tile[tx][i]);
}

// ---------------------------------------------------------------- layernorm -> bf16
__launch_bounds__(256)
__global__ void ln_kernel(const float* __restrict__ x, const float* __restrict__ g,
                          const float* __restrict__ be, u16* __restrict__ y)
{
    int row = blockIdx.x * 4 + (threadIdx.x >> 6);
    int lane = threadIdx.x & 63;
    if (row >= MROWS) return;
    const float* xr = x + (long)row * DIM;
    float v[12];
    float s = 0.f;
    #pragma unroll
    for (int i = 0; i < 12; ++i) { v[i] = xr[lane + 64 * i]; s += v[i]; }
    for (int off = 32; off; off >>= 1) s += __shfl_down(s, off, 64);
    s = __shfl(s, 0, 64);
    float mean = s * (1.f / 768.f);
    float vs = 0.f;
    #pragma unroll
    for (int i = 0; i < 12; ++i) { float d = v[i] - mean; vs += d * d; }
    for (int off = 32; off; off >>= 1) vs += __shfl_down(vs, off, 64);
    vs = __shfl(vs, 0, 64);
    float inv = rsqrtf(vs * (1.f / 768.f) + 1e-5f);
    u16* yr = y + (long)row * DIM;
    #pragma unroll
    for (int i = 0; i < 12; ++i) {
        int j = lane + 64 * i;
        yr[j] = f2bf((v[i] - mean) * inv * g[j] + be[j]);
    }
}

// ---------------------------------------------------------------- bf16 MFMA GEMM
// A[M,K] bf16 row-major, Wt[N,K] bf16 row-major.  C = A @ Wt^T + bias.
// MODE 0: out fp32, += res (fp32).  MODE 1: relu, out bf16.  MODE 2: out fp32 in
// qkv-permuted layout [which][b*16+h][s][48], q pre-scaled by 1/sqrt(48).
// BM=128, BK=64; BN template (128 or 64). 4 waves, each computes 64 x (BN/2).
template<int BN, int MODE>
__launch_bounds__(256)
__global__ void gemm_mfma(const u16* __restrict__ A, const u16* __restrict__ Wt,
                          const float* __restrict__ bias, const float* __restrict__ res,
                          void* __restrict__ outv, int M, int N, int K)
{
    constexpr int NSUB = BN / 16;
    constexpr int NJ = NSUB / 2;
    constexpr int NB = (BN * 8) / 256;
    __shared__ u16 As[2 * 8 * 64 * 8];       // 16 KB
    __shared__ u16 Bs[2 * NSUB * 64 * 8];    // 16 / 8 KB

    int tid = threadIdx.x;
    int lane = tid & 63;
    int w = tid >> 6, wm = w >> 1, wn = w & 1;
    int m0 = blockIdx.y * 128, n0 = blockIdx.x * BN;

    floatx4 acc[4][NJ];
    #pragma unroll
    for (int i = 0; i < 4; ++i)
        #pragma unroll
        for (int j = 0; j < NJ; ++j) acc[i][j] = (floatx4){0.f, 0.f, 0.f, 0.f};

    int lm = lane & 15, lk = lane >> 4;      // fragment (m, kgroup)

    for (int k0 = 0; k0 < K; k0 += 64) {
        __syncthreads();
        #pragma unroll
        for (int i = 0; i < 4; ++i) {        // A: 128 rows x 8 chunks
            int q = tid + 256 * i;
            int r = q >> 3, c = q & 7;
            int gr = m0 + r; if (gr >= M) gr = M - 1;
            int4 v = *(const int4*)(A + (long)gr * K + k0 + c * 8);
            int off = (((c >> 2) * 8 + (r >> 4)) * 64 + (r & 15) * 4 + (c & 3)) * 8;
            *(int4*)&As[off] = v;
        }
        #pragma unroll
        for (int i = 0; i < NB; ++i) {       // B: BN rows x 8 chunks
            int q = tid + 256 * i;
            int r = q >> 3, c = q & 7;
            int4 v = *(const int4*)(Wt + (long)(n0 + r) * K + k0 + c * 8);
            int off = (((c >> 2) * NSUB + (r >> 4)) * 64 + (r & 15) * 4 + (c & 3)) * 8;
            *(int4*)&Bs[off] = v;
        }
        __syncthreads();
        #pragma unroll
        for (int t = 0; t < 2; ++t) {
            short8 af[4];
            #pragma unroll
            for (int i = 0; i < 4; ++i)
                af[i] = *(const short8*)&As[((t * 8 + wm * 4 + i) * 64 + lm * 4 + lk) * 8];
            short8 bfr[NJ];
            #pragma unroll
            for (int j = 0; j < NJ; ++j)
                bfr[j] = *(const short8*)&Bs[((t * NSUB + wn * NJ + j) * 64 + lm * 4 + lk) * 8];
            #pragma unroll
            for (int i = 0; i < 4; ++i)
                #pragma unroll
                for (int j = 0; j < NJ; ++j)
                    acc[i][j] = __builtin_amdgcn_mfma_f32_16x16x32_bf16(af[i], bfr[j], acc[i][j], 0, 0, 0);
        }
    }

    // epilogue: C row = m0 + wm*64 + i*16 + (lane>>4)*4 + rr, col = n0 + wn*NJ*16 + j*16 + (lane&15)
    #pragma unroll
    for (int j = 0; j < NJ; ++j) {
        int col = n0 + wn * (NJ * 16) + j * 16 + lm;
        float bv = bias[col];
        #pragma unroll
        for (int i = 0; i < 4; ++i) {
            int rbase = m0 + wm * 64 + i * 16 + lk * 4;
            #pragma unroll
            for (int rr = 0; rr < 4; ++rr) {
                int row = rbase + rr;
                if (row >= M) continue;
                float val = acc[i][j][rr] + bv;
                if (MODE == 0) {
                    val += res[(long)row * N + col];
                    ((float*)outv)[(long)row * N + col] = val;
                } else if (MODE == 1) {
                    val = fmaxf(val, 0.f);
                    ((u16*)outv)[(long)row * N + col] = f2bf(val);
                } else {
                    int which = col >= 1536 ? 2 : (col >= 768 ? 1 : 0);
                    int rem = col - which * 768;
                    int h = rem / 48, d = rem - h * 48;
                    if (which == 0) val *= 0.14433756729740643f;
                    int b = row / SMAXT, s = row - b * SMAXT;
                    ((float*)outv)[(long)which * QKVPLANE + ((long)(b * 16 + h) * SMAXT + s) * 48 + d] = val;
                }
            }
        }
    }
}

// ---------------------------------------------------------------- attention (fp32, head-major qkv, q pre-scaled)
__launch_bounds__(256)
__global__ void attn_kernel(const float* __restrict__ qkv, u16* __restrict__ o, int S)
{
    int bh = blockIdx.y;                 // b*16 + h
    int b = bh >> 4, h = bh & 15;
    int q0 = blockIdx.x * 16;
    if (q0 >= S) return;
    __shared__ float qs[16][48];
    __shared__ float kbuf[3328];         // Ks[64][52] OR VsT[48][68]
    __shared__ float sc[16][304];
    int t = threadIdx.x;
    const float* qp = qkv + (long)bh * SMAXT * 48;
    const float* kp = qp + QKVPLANE;
    const float* vp = qp + 2 * QKVPLANE;

    for (int lin = t; lin < 16 * 48; lin += 256) {
        int i2 = lin / 48, d = lin % 48;
        int qi2 = q0 + i2; if (qi2 > S - 1) qi2 = S - 1;
        qs[i2][d] = qp[(long)qi2 * 48 + d];
    }
    __syncthreads();
    int i = t >> 4, j = t & 15;
    int qi = q0 + i;
    float4 q4[12];
    #pragma unroll
    for (int k4 = 0; k4 < 12; ++k4) q4[k4] = *(const float4*)&qs[i][k4 * 4];

    // ---- scores
    for (int s0 = 0; s0 < S; s0 += 64) {
        int ns = S - s0; if (ns > 64) ns = 64;
        __syncthreads();
        for (int lin = t; lin < 64 * 12; lin += 256) {
            int ss = lin / 12, d4 = lin % 12;
            float4 kv = make_float4(0.f, 0.f, 0.f, 0.f);
            if (ss < ns) kv = *(const float4*)(kp + (long)(s0 + ss) * 48 + d4 * 4);
            *(float4*)&kbuf[ss * 52 + d4 * 4] = kv;
        }
        __syncthreads();
        #pragma unroll
        for (int u = 0; u < 4; ++u) {
            int ss = j + 16 * u;
            float acc = 0.f;
            #pragma unroll
            for (int k4 = 0; k4 < 12; ++k4) {
                float4 kk = *(const float4*)&kbuf[ss * 52 + k4 * 4];
                acc += q4[k4].x * kk.x + q4[k4].y * kk.y + q4[k4].z * kk.z + q4[k4].w * kk.w;
            }
            int s = s0 + ss;
            if (ss < ns) {
                bool masked = (qi >= CCTX) && (s > qi);
                sc[i][s] = masked ? acc + NEGV : acc;
            }
        }
    }
    __syncthreads();

    // ---- softmax
    float mx = -1e30f;
    for (int s = j; s < S; s += 16) mx = fmaxf(mx, sc[i][s]);
    #pragma unroll
    for (int m = 8; m; m >>= 1) mx = fmaxf(mx, __shfl_xor(mx, m, 16));
    int Sp = (S + 3) & ~3;
    float sum = 0.f;
    for (int s = j; s < Sp; s += 16) {
        float e = (s < S) ? __expf(sc[i][s] - mx) : 0.f;
        sc[i][s] = e; sum += e;
    }
    #pragma unroll
    for (int m = 8; m; m >>= 1) sum += __shfl_xor(sum, m, 16);
    float inv = 1.f / sum;

    // ---- o = softmax @ V
    float oc0 = 0.f, oc1 = 0.f, oc2 = 0.f;
    int d0 = j * 3;
    for (int s0 = 0; s0 < S; s0 += 64) {
        int ns4 = Sp - s0; if (ns4 > 64) ns4 = 64;
        __syncthreads();
        for (int lin = t; lin < 64 * 48; lin += 256) {
            int ss = lin / 48, d = lin % 48;
            float v = 0.f;
            int s = s0 + ss;
            if (s < S) v = vp[(long)s * 48 + d];
            kbuf[d * 68 + ss] = v;
        }
        __syncthreads();
        for (int sb = 0; sb < ns4; sb += 4) {
            float4 a4 = *(const float4*)&sc[i][s0 + sb];
            float4 v0 = *(const float4*)&kbuf[d0 * 68 + sb];
            float4 v1 = *(const float4*)&kbuf[(d0 + 1) * 68 + sb];
            float4 v2 = *(const float4*)&kbuf[(d0 + 2) * 68 + sb];
            oc0 += a4.x * v0.x + a4.y * v0.y + a4.z * v0.z + a4.w * v0.w;
            oc1 += a4.x * v1.x + a4.y * v1.y + a4.z * v1.z + a4.w * v1.w;
            oc2 += a4.x * v2.x + a4.y * v2.y + a4.z * v2.z + a4.w * v2.w;
        }
    }
    if (qi < S) {
        u16* orow = o + ((long)(b * SMAXT + qi)) * 768 + h * 48 + d0;
        orow[0] = f2bf(oc0 * inv); orow[1] = f2bf(oc1 * inv); orow[2] = f2bf(oc2 * inv);
    }
}

// ---------------------------------------------------------------- decoder gelu GEMM (4x768 @ 768x768), fp32
__launch_bounds__(256)
__global__ void dec_gelu(const float* __restrict__ src, long srowstride,
                         const float* __restrict__ W, const float* __restrict__ bias,
                         float* __restrict__ dst)
{
    int b = blockIdx.y;
    int jb = blockIdx.x;
    __shared__ float s0buf[768];
    __shared__ float red[4][64];
    int tid = threadIdx.x;
    const float* sr = src + (long)b * srowstride;
    for (int i = tid; i < 768; i += 256) s0buf[i] = sr[i];
    __syncthreads();
    int jj = tid & 63, ig = tid >> 6;
    int jcol = jb * 64 + jj;
    float acc = 0.f;
    const float* wp = W + (long)(ig * 192) * 768 + jcol;
    #pragma unroll 4
    for (int i = 0; i < 192; ++i) acc += s0buf[ig * 192 + i] * wp[(long)i * 768];
    red[ig][jj] = acc;
    __syncthreads();
    if (ig == 0) {
        float a = red[0][jj] + red[1][jj] + red[2][jj] + red[3][jj] + bias[jcol];
        dst[(long)b * 768 + jcol] = gelu_f(a);
    }
}

// ---------------------------------------------------------------- decoder final
__launch_bounds__(256)
__global__ void dec_final(const float* __restrict__ d2, const float* __restrict__ Wd3,
                          const float* __restrict__ bd3, const float* __restrict__ Wpp,
                          const float* __restrict__ bpp, const float* __restrict__ gpp,
                          const float* __restrict__ bepp, float* __restrict__ out,
                          float* __restrict__ X, int t)
{
    int b = blockIdx.x;
    int tid = threadIdx.x;
    __shared__ float red[2][4];
    __shared__ float pp[2];
    const float* dr = d2 + (long)b * 768;
    float a0 = 0.f, a1 = 0.f;
    for (int i = tid; i < 768; i += 256) {
        float v = dr[i];
        a0 += v * Wd3[2 * i]; a1 += v * Wd3[2 * i + 1];
    }
    for (int off = 32; off; off >>= 1) { a0 += __shfl_down(a0, off, 64); a1 += __shfl_down(a1, off, 64); }
    int wid = tid >> 6, lane = tid & 63;
    if (!lane) { red[0][wid] = a0; red[1][wid] = a1; }
    __syncthreads();
    if (!tid) {
        float p0 = red[0][0] + red[0][1] + red[0][2] + red[0][3] + bd3[0];
        float p1 = red[1][0] + red[1][1] + red[1][2] + red[1][3] + bd3[1];
        out[(long)(b * NFUT + t) * 2 + 0] = p0;
        out[(long)(b * NFUT + t) * 2 + 1] = p1;
        pp[0] = p0; pp[1] = p1;
    }
    __syncthreads();
    if (t == NFUT - 1) return;
    float p0 = pp[0], p1 = pp[1];
    float pv[3]; float s = 0.f;
    #pragma unroll
    for (int u = 0; u < 3; ++u) {
        int jcol = tid + 256 * u;
        pv[u] = p0 * Wpp[jcol] + p1 * Wpp[768 + jcol] + bpp[jcol];
        s += pv[u];
    }
    for (int off = 32; off; off >>= 1) s += __shfl_down(s, off, 64);
    __syncthreads();
    if (!lane) red[0][wid] = s;
    __syncthreads();
    float mean = (red[0][0] + red[0][1] + red[0][2] + red[0][3]) * (1.f / 768.f);
    float vs = 0.f;
    #pragma unroll
    for (int u = 0; u < 3; ++u) { float d = pv[u] - mean; vs += d * d; }
    for (int off = 32; off; off >>= 1) vs += __shfl_down(vs, off, 64);
    __syncthreads();
    if (!lane) red[1][wid] = vs;
    __syncthreads();
    float var = (red[1][0] + red[1][1] + red[1][2] + red[1][3]) * (1.f / 768.f);
    float inv = rsqrtf(var + 1e-5f);
    float* Xr = X + ((long)(b * SMAXT + CCTX + t + 1)) * 768;
    #pragma unroll
    for (int u = 0; u < 3; ++u) {
        int jcol = tid + 256 * u;
        float y = (pv[u] - mean) * inv * gpp[jcol] + bepp[jcol];
        if (y > 0.f) Xr[jcol] += y;
    }
}

// ---------------------------------------------------------------- launch
extern "C" void kernel_launch(void* const* d_in, const int* in_sizes, int n_in,
                              void* d_out, int out_size, void* d_ws, size_t ws_size,
                              hipStream_t stream)
{
    const float* img    = (const float*)d_in[0];
    const float* past   = (const float*)d_in[1];
    const int*   intent = (const int*)d_in[2];
    const float* pos    = (const float*)d_in[3];
    const float* futq   = (const float*)d_in[4];
    const float* iemb   = (const float*)d_in[5];
    const float* temb   = (const float*)d_in[6];
    const float* W_past = (const float*)d_in[7];
    const float* b_past = (const float*)d_in[8];
    const float* W_ppos = (const float*)d_in[9];
    const float* b_ppos = (const float*)d_in[10];
    const float* W_pp   = (const float*)d_in[11];
    const float* b_pp   = (const float*)d_in[12];
    const float* g_pp   = (const float*)d_in[13];
    const float* be_pp  = (const float*)d_in[14];
    const float* Wqkv   = (const float*)d_in[15];
    const float* bqkv   = (const float*)d_in[16];
    const float* Wo     = (const float*)d_in[17];
    const float* bo     = (const float*)d_in[18];
    const float* g1     = (const float*)d_in[19];
    const float* beta1  = (const float*)d_in[20];
    const float* g2     = (const float*)d_in[21];
    const float* beta2  = (const float*)d_in[22];
    const float* W1     = (const float*)d_in[23];
    const float* bf1    = (const float*)d_in[24];
    const float* W2     = (const float*)d_in[25];
    const float* bf2    = (const float*)d_in[26];
    const float* Wd1    = (const float*)d_in[27];
    const float* bd1    = (const float*)d_in[28];
    const float* Wd2    = (const float*)d_in[29];
    const float* bd2    = (const float*)d_in[30];
    const float* Wd3    = (const float*)d_in[31];
    const float* bd3    = (const float*)d_in[32];
    float* out = (float*)d_out;

    float* ws     = (float*)d_ws;
    float* Xb     = ws;                      // 900096 f
    float* xbuf   = ws + 900096;             // 900096 f
    float* qkvbuf = ws + 1800192;            // 2700288 f (permuted q|k|v planes)
    u16*   hbuf   = (u16*)(ws + 4500480);    // 900096 bf16
    u16*   aobuf  = (u16*)(ws + 4950528);    // 900096 bf16
    u16*   big    = (u16*)(ws + 5400576);    // 1172*3072 bf16
    float* d1ws   = ws + 7200768;            // 3072 f
    float* d2ws   = ws + 7203840;            // 3072 f
    u16*   WqkvT  = (u16*)(ws + 7206912);    // 3*2304*768 bf16
    u16*   WoT    = (u16*)(ws + 9861120);    // 3*768*768
    u16*   W1T    = (u16*)(ws + 10745856);   // 3*3072*768
    u16*   W2T    = (u16*)(ws + 14284800);   // 3*768*3072

    // one-time per launch: weights -> bf16 [N,K]
    convert_transpose<<<dim3(2304/32, 768/32, 3), 256, 0, stream>>>(Wqkv, WqkvT, 768, 2304);
    convert_transpose<<<dim3(768/32, 768/32, 3), 256, 0, stream>>>(Wo, WoT, 768, 768);
    convert_transpose<<<dim3(3072/32, 768/32, 3), 256, 0, stream>>>(W1, W1T, 768, 3072);
    convert_transpose<<<dim3(768/32, 3072/32, 3), 256, 0, stream>>>(W2, W2T, 3072, 768);

    init_base<<<dim3(MROWS), dim3(256), 0, stream>>>(img, past, intent, pos, futq, iemb,
                                                     temb, W_past, b_past, W_ppos, b_ppos, Xb);

    for (int t = 0; t < NFUT; ++t) {
        int S = CCTX + t + 1;
        const float* src = Xb;
        for (int l = 0; l < NLAY; ++l) {
            ln_kernel<<<dim3(293), dim3(256), 0, stream>>>(src, g1 + l * 768, beta1 + l * 768, hbuf);
            gemm_mfma<128, 2><<<dim3(18, 10), dim3(256), 0, stream>>>(
                hbuf, WqkvT + (long)l * 768 * 2304, bqkv + l * 2304, nullptr, qkvbuf, MROWS, 2304, 768);
            attn_kernel<<<dim3((S + 15) / 16, 64), dim3(256), 0, stream>>>(qkvbuf, aobuf, S);
            gemm_mfma<64, 0><<<dim3(12, 10), dim3(256), 0, stream>>>(
                aobuf, WoT + (long)l * 768 * 768, bo + l * 768, src, xbuf, MROWS, 768, 768);
            ln_kernel<<<dim3(293), dim3(256), 0, stream>>>(xbuf, g2 + l * 768, beta2 + l * 768, hbuf);
            gemm_mfma<128, 1><<<dim3(24, 10), dim3(256), 0, stream>>>(
                hbuf, W1T + (long)l * 768 * 3072, bf1 + l * 3072, nullptr, big, MROWS, 3072, 768);
            gemm_mfma<64, 0><<<dim3(12, 10), dim3(256), 0, stream>>>(
                big, W2T + (long)l * 3072 * 768, bf2 + l * 768, xbuf, xbuf, MROWS, 768, 3072);
            src = xbuf;
        }
        dec_gelu<<<dim3(12, 4), dim3(256), 0, stream>>>(xbuf + (long)(S - 1) * 768, (long)SMAXT * 768, Wd1, bd1, d1ws);
        dec_gelu<<<dim3(12, 4), dim3(256), 0, stream>>>(d1ws, 768L, Wd2, bd2, d2ws);
        dec_final<<<dim3(4), dim3(256), 0, stream>>>(d2ws, Wd3, bd3, W_pp, b_pp, g_pp, be_pp, out, Xb, t);
    }
}